// Round 1
// baseline (797.446 us; speedup 1.0000x reference)
//
#include <hip/hip_runtime.h>

#define HH 32
#define WW 32
#define CIN 64
#define COUT 64
#define BATCH 32
#define KTOT 576            // CIN * 9
#define NPOS 1024
#define KC 16               // k-chunk per wave-iteration
#define KHALF 288           // K per wave (2-way K-split)
#define NCW 18              // chunks per wave = 288/16

// halo-padded transposed input: xT[i][34][34][b]
__device__ float g_xT[CIN * 34 * 34 * BATCH];

// Coalesced transpose repack: one block per (i, hh). Reads x rows (lanes over
// w, 128 B segments), transposes through LDS, writes g_xT rows (lanes over b,
// 128 B segments). Halo rows/cols written as zeros.
__global__ __launch_bounds__(256) void repack_kernel(const float* __restrict__ x) {
    __shared__ float tile[32 * 33];        // [b][w], pad 33 -> conflict-free
    const int i   = blockIdx.x;            // 0..63
    const int hh  = blockIdx.y;            // 0..33
    const int tid = threadIdx.x;

    float* dst = &g_xT[((i * 34 + hh) * 34) * BATCH];

    if (hh == 0 || hh == 33) {             // halo row: all zeros (34*32 floats)
        for (int idx = tid; idx < 34 * BATCH; idx += 256) dst[idx] = 0.f;
        return;
    }
    const int hs = hh - 1;
#pragma unroll
    for (int bb = 0; bb < 4; ++bb) {       // read 8 b-rows per pass
        int b = bb * 8 + (tid >> 5);
        int w = tid & 31;
        tile[b * 33 + w] = x[(b << 16) + (i << 10) + (hs << 5) + w];
    }
    __syncthreads();
#pragma unroll
    for (int q = 0; q < 5; ++q) {          // write 8 ww-rows per pass (34 total)
        int ww = q * 8 + (tid >> 5);
        if (ww < 34) {
            int b = tid & 31;
            float v = (ww == 0 || ww == 33) ? 0.f : tile[b * 33 + (ww - 1)];
            dst[ww * BATCH + b] = v;
        }
    }
}

__device__ __forceinline__ void async16(const void* src, void* dst_lds) {
    __builtin_amdgcn_global_load_lds(
        (const __attribute__((address_space(1))) void*)src,
        (__attribute__((address_space(3))) void*)dst_lds,
        16, 0, 0);
}

// 128 threads = 2 waves per block; block = (position p, cout-half oh).
// Wave wv computes K in [wv*288, wv*288+288) over 32 couts x 32 batch.
// 2-deep LDS pipeline, 4 DMAs per chunk -> vmcnt(4) = chunk c landed.
// Grid 2048 -> 8 blocks/CU (LDS 16.4 KB) -> 4 waves/SIMD.
__global__ __launch_bounds__(128, 4) void local2d_kernel(
    const float* __restrict__ weight,
    const float* __restrict__ bias,
    float* __restrict__ out)
{
    // manual LDS partition (floats):
    //   [wv*1024 + s*512]        : W buffers (2 waves x 2 bufs x 512)
    //   [2048 + wv*1024 + s*512] : P buffers (2 waves x 2 bufs x 512)
    //   [0..1152)                : reduction scratch (after both waves done)
    __shared__ __align__(16) float lds[4096];

    const int wv = threadIdx.x >> 6;       // wave id 0/1
    const int l  = threadIdx.x & 63;       // lane

    const int og = l & 7, bg = l >> 3;     // compute roles: o-group, b-group

    // XCD swizzle: xcd = bid&7; within an XCD, the two oh-halves of a position
    // are consecutive in time (P L2-reuse, contiguous 147 KB W stream), and
    // each XCD owns whole output rows y (full 128 B out lines per XCD).
    int bid = blockIdx.x;
    int xcd = bid & 7;
    int t   = bid >> 3;                    // 0..255
    int oh  = t & 1;                       // cout half
    int tt  = t >> 1;                      // 0..127
    int y   = ((tt >> 5) << 3) | xcd;      // {xcd, 8+xcd, 16+xcd, 24+xcd}
    int xw  = tt & 31;
    int p   = (y << 5) | xw;               // position = y*32 + x

    const int kbase = wv * KHALF;
    const float* wpos = weight + ((long)p * COUT + (oh << 5)) * KTOT;

    // W DMA source permutation (m173: per-lane global src + linear LDS dst).
    // LDS granule layout: idx = kkq*32 + oo*8 + og  (granule = 4 floats).
    // DMA d writes granules [d*64, d*64+64): lane l -> idx = d*64 + l:
    //   g (k-granule) = d*2 + (l>>5), rem = l&31, o = (rem&7)*4 + (rem>>3).
    // Read at fixed (kkq,oo): 8 og lanes hit 8 consecutive granules = 128 B
    // spanning all 32 banks -> conflict-free.
    const int rem = l & 31;
    const int wo  = ((rem & 7) << 2) + (rem >> 3);
    const float* wsrc0 = wpos + wo * KTOT + kbase + ((l >> 5) << 2);

    float* Wb = &lds[wv << 10];
    float* Pb = &lds[2048 + (wv << 10)];

    float acc[4][4];
#pragma unroll
    for (int a = 0; a < 4; ++a)
#pragma unroll
        for (int c = 0; c < 4; ++c) acc[a][c] = 0.f;

    auto stage = [&](int c, int bsel) {
        const float* ws = wsrc0 + c * KC;
        float* wdst = Wb + (bsel << 9);
        async16(ws,     wdst);             // granules   0..63 (g 0,1)
        async16(ws + 8, wdst + 256);       // granules 64..127 (g 2,3)
        // P chunk: 16 k x 32 b; DMA q covers 8 k-rows = 1024 B contig
#pragma unroll
        for (int q = 0; q < 2; ++q) {
            int k  = kbase + c * KC + (q << 3) + (l >> 3);
            int i  = k / 9;
            int r  = k - i * 9;
            int kh = r / 3;
            int kw = r - kh * 3;
            const float* ps =
                &g_xT[(((i * 34) + y + kh) * 34 + xw + kw) * BATCH + ((l & 7) << 2)];
            async16(ps, Pb + (bsel << 9) + (q << 8));
        }
    };

    auto compute = [&](int bsel) {
        const float* Wc = Wb + (bsel << 9);
        const float* Pc = Pb + (bsel << 9) + (bg << 2);
#pragma unroll
        for (int kkq = 0; kkq < 4; ++kkq) {
            float4 pr[4];
#pragma unroll
            for (int j = 0; j < 4; ++j)
                pr[j] = *(const float4*)(Pc + ((kkq << 2) + j) * BATCH);
            const float* prf = (const float*)pr;
#pragma unroll
            for (int oo = 0; oo < 4; ++oo) {
                float4 wr = *(const float4*)(Wc + (kkq << 7) + (oo << 5) + (og << 2));
#pragma unroll
                for (int bb = 0; bb < 4; ++bb) {
                    float a = acc[oo][bb];
                    a = fmaf(wr.x, prf[0 * 4 + bb], a);
                    a = fmaf(wr.y, prf[1 * 4 + bb], a);
                    a = fmaf(wr.z, prf[2 * 4 + bb], a);
                    a = fmaf(wr.w, prf[3 * 4 + bb], a);
                    acc[oo][bb] = a;
                }
            }
        }
    };

    stage(0, 0);
    stage(1, 1);
#pragma unroll 2
    for (int c = 0; c < NCW; ++c) {
        if (c < NCW - 1) {
            // chunk c's 4 DMAs are the oldest; <=4 left => chunk c landed,
            // chunk c+1 still in flight across the compute phase.
            asm volatile("s_waitcnt vmcnt(4)" ::: "memory");
        } else {
            asm volatile("s_waitcnt vmcnt(0)" ::: "memory");
        }
        compute(c & 1);
        if (c + 2 < NCW) {
            // WAR guard: compute(c)'s ds_reads of buf c&1 must complete
            // before chunk c+2's DMAs overwrite it (~120 cy, not 12K).
            asm volatile("s_waitcnt lgkmcnt(0)" ::: "memory");
            stage(c + 2, c & 1);
        }
    }

    // ---- cross-wave reduction: wave1 dumps partials, wave0 sums + stores ----
    __syncthreads();                       // both waves done with staging bufs
    float* R = &lds[0];                    // 32 o x 32 b, stride 36 (bank spread)
    if (wv == 1) {
#pragma unroll
        for (int oo = 0; oo < 4; ++oo) {
            int o = (og << 2) + oo;
            *(float4*)(&R[o * 36 + (bg << 2)]) =
                make_float4(acc[oo][0], acc[oo][1], acc[oo][2], acc[oo][3]);
        }
    }
    __syncthreads();
    if (wv == 0) {
#pragma unroll
        for (int oo = 0; oo < 4; ++oo) {
            int o  = (og << 2) + oo;
            int of = (oh << 5) + o;        // global cout
            float bv = bias[(of << 10) + p];
            float4 r = *(const float4*)(&R[o * 36 + (bg << 2)]);
            const float* rf = (const float*)&r;
#pragma unroll
            for (int bb = 0; bb < 4; ++bb) {
                int b = (bg << 2) + bb;
                out[(b << 16) + (of << 10) + p] = acc[oo][bb] + rf[bb] + bv;
            }
        }
    }
}

extern "C" void kernel_launch(void* const* d_in, const int* in_sizes, int n_in,
                              void* d_out, int out_size, void* d_ws, size_t ws_size,
                              hipStream_t stream) {
    const float* x      = (const float*)d_in[0];
    const float* weight = (const float*)d_in[1];
    const float* bias   = (const float*)d_in[2];
    float* out          = (float*)d_out;

    hipLaunchKernelGGL(repack_kernel, dim3(CIN, 34), dim3(256), 0, stream, x);
    hipLaunchKernelGGL(local2d_kernel, dim3(2 * NPOS), dim3(128), 0, stream,
                       weight, bias, out);
}

// Round 2
// 470.361 us; speedup vs baseline: 1.6954x; 1.6954x over previous
//
#include <hip/hip_runtime.h>

#define HH 32
#define WW 32
#define CIN 64
#define COUT 64
#define BATCH 32
#define KTOT 576            // CIN * 9
#define NPOS 1024
#define KC 16               // k-chunk per wave-iteration
#define KHALF 288           // K per wave (2-way K-split)
#define NCW 18              // chunks per wave = 288/16
#define WGRP 260            // 16 o-rows * 16 k + 4 floats pad (16B-aligned group stride)

// halo-padded transposed input: xT[i][34][34][b]
__device__ float g_xT[CIN * 34 * 34 * BATCH];

// Coalesced transpose repack: one block per (i, hh). Reads x rows (lanes over
// w, 128 B segments), transposes through LDS, writes g_xT rows (lanes over b,
// 128 B segments). Halo rows/cols written as zeros.
__global__ __launch_bounds__(256) void repack_kernel(const float* __restrict__ x) {
    __shared__ float tile[32 * 33];        // [b][w], pad 33 -> conflict-free
    const int i   = blockIdx.x;            // 0..63
    const int hh  = blockIdx.y;            // 0..33
    const int tid = threadIdx.x;

    float* dst = &g_xT[((i * 34 + hh) * 34) * BATCH];

    if (hh == 0 || hh == 33) {             // halo row: all zeros (34*32 floats)
        for (int idx = tid; idx < 34 * BATCH; idx += 256) dst[idx] = 0.f;
        return;
    }
    const int hs = hh - 1;
#pragma unroll
    for (int bb = 0; bb < 4; ++bb) {       // read 8 b-rows per pass
        int b = bb * 8 + (tid >> 5);
        int w = tid & 31;
        tile[b * 33 + w] = x[(b << 16) + (i << 10) + (hs << 5) + w];
    }
    __syncthreads();
#pragma unroll
    for (int q = 0; q < 5; ++q) {          // write 8 ww-rows per pass (34 total)
        int ww = q * 8 + (tid >> 5);
        if (ww < 34) {
            int b = tid & 31;
            float v = (ww == 0 || ww == 33) ? 0.f : tile[b * 33 + (ww - 1)];
            dst[ww * BATCH + b] = v;
        }
    }
}

__device__ __forceinline__ void async16(const void* src, void* dst_lds) {
    __builtin_amdgcn_global_load_lds(
        (const __attribute__((address_space(1))) void*)src,
        (__attribute__((address_space(3))) void*)dst_lds,
        16, 0, 0);
}

// 128 threads = 2 waves per block; wave w computes K in [w*288, w*288+288).
// 2-deep LDS pipeline per wave; 6 DMAs per chunk -> vmcnt(6) = chunk c landed
// (chunk c+1 still in flight across the compute phase).
// LDS 24.8 KB -> 6 blocks/CU -> 3 waves/SIMD (vs 2 at the 3-deep 37.4 KB).
__global__ __launch_bounds__(128, 3) void local2d_kernel(
    const float* __restrict__ weight,
    const float* __restrict__ bias,
    float* __restrict__ out)
{
    // per-wave private staging: [wave][buf][...]
    __shared__ float Wl[2][2][4 * WGRP];   // 4 groups x (16 o-rows x 16 k + pad)
    __shared__ float Pl[2][2][KC * BATCH]; // 16 k x 32 b

    const int wv = threadIdx.x >> 6;       // wave id 0/1
    const int l  = threadIdx.x & 63;       // lane

    const int og = l & 7, bg = l >> 3;     // compute roles: o-group, b-group

    // row-granular XCD swizzle: each XCD owns whole output rows ->
    // 32-consecutive-p runs = full 128 B out lines from one XCD; W stream and
    // g_xT row reads contiguous per XCD.
    int bid = blockIdx.x;
    int xcd = bid & 7;
    int t   = bid >> 3;                    // 0..127
    int y   = ((t >> 5) << 3) | xcd;       // {xcd, 8+xcd, 16+xcd, 24+xcd}
    int xw  = t & 31;
    int p   = (y << 5) | xw;               // position = y*32 + x

    const int kbase = wv * KHALF;
    const float* wpos  = weight + (long)p * (COUT * KTOT);
    // W DMA lane role: row l>>2 (of 16-row group), col (l&3)*4 floats
    const float* wsrc0 = wpos + (l >> 2) * KTOT + ((l & 3) << 2) + kbase;

    float acc[8][4];
#pragma unroll
    for (int a = 0; a < 8; ++a)
#pragma unroll
        for (int c = 0; c < 4; ++c) acc[a][c] = 0.f;

    auto stage = [&](int c, int bsel) {
        const float* ws = wsrc0 + c * KC;
        // W chunk: 64 o x 16 k; DMA g covers o-rows [16g,16g+16)
#pragma unroll
        for (int g = 0; g < 4; ++g)
            async16(ws + g * (16 * KTOT), &Wl[wv][bsel][g * WGRP]);
        // P chunk: 16 k x 32 b; DMA q covers 8 k-rows = 1024 B contig
#pragma unroll
        for (int q = 0; q < 2; ++q) {
            int k  = kbase + c * KC + (q << 3) + (l >> 3);
            int i  = k / 9;
            int r  = k - i * 9;
            int kh = r / 3;
            int kw = r - kh * 3;
            const float* ps =
                &g_xT[(((i * 34) + y + kh) * 34 + xw + kw) * BATCH + ((l & 7) << 2)];
            async16(ps, &Pl[wv][bsel][q * (8 * BATCH)]);
        }
    };

    auto compute = [&](int bsel) {
        // lane reads o = og*8+oo -> group og>>1, row (og&1)*8+oo
        const float* Wb = &Wl[wv][bsel][(og >> 1) * WGRP + ((og & 1) << 3) * 16];
        const float* Pb = &Pl[wv][bsel][bg << 2];
#pragma unroll
        for (int kk = 0; kk < KC; kk += 4) {
            float4 pr[4];
#pragma unroll
            for (int j = 0; j < 4; ++j)
                pr[j] = *(const float4*)(Pb + (kk + j) * BATCH);
            const float* prf = (const float*)pr;
#pragma unroll
            for (int oo = 0; oo < 8; ++oo) {
                float4 wr = *(const float4*)(Wb + oo * KC + kk);
#pragma unroll
                for (int bb = 0; bb < 4; ++bb) {
                    float a = acc[oo][bb];
                    a = fmaf(wr.x, prf[0 * 4 + bb], a);
                    a = fmaf(wr.y, prf[1 * 4 + bb], a);
                    a = fmaf(wr.z, prf[2 * 4 + bb], a);
                    a = fmaf(wr.w, prf[3 * 4 + bb], a);
                    acc[oo][bb] = a;
                }
            }
        }
    };

    stage(0, 0);
    stage(1, 1);
    for (int c = 0; c < NCW; ++c) {
        if (c < NCW - 1) {
            // chunk c's 6 DMAs are the oldest; <=6 left => chunk c landed,
            // chunk c+1 still covering this compute phase.
            asm volatile("s_waitcnt vmcnt(6)" ::: "memory");
        } else {
            asm volatile("s_waitcnt vmcnt(0)" ::: "memory");
        }
        compute(c & 1);
        if (c + 2 < NCW) {
            // WAR guard: compute(c)'s ds_reads of buf c&1 must retire before
            // chunk c+2's DMAs overwrite that buffer (~120 cy, near-free).
            asm volatile("s_waitcnt lgkmcnt(0)" ::: "memory");
            stage(c + 2, c & 1);
        }
    }

    // ---- cross-wave reduction: wave1 dumps partials, wave0 sums + stores ----
    __syncthreads();                       // both waves done with staging bufs
    float* R = &Wl[0][0][0];               // 64 o x 32 b, stride 36 (bank spread)
    if (wv == 1) {
#pragma unroll
        for (int oo = 0; oo < 8; ++oo) {
            int o = (og << 3) + oo;
            *(float4*)(&R[o * 36 + (bg << 2)]) =
                make_float4(acc[oo][0], acc[oo][1], acc[oo][2], acc[oo][3]);
        }
    }
    __syncthreads();
    if (wv == 0) {
#pragma unroll
        for (int oo = 0; oo < 8; ++oo) {
            int o = (og << 3) + oo;
            float bv = bias[(o << 10) + p];
            float4 r = *(const float4*)(&R[o * 36 + (bg << 2)]);
            const float* rf = (const float*)&r;
#pragma unroll
            for (int bb = 0; bb < 4; ++bb) {
                int b = (bg << 2) + bb;
                out[(b << 16) + (o << 10) + p] = acc[oo][bb] + rf[bb] + bv;
            }
        }
    }
}

extern "C" void kernel_launch(void* const* d_in, const int* in_sizes, int n_in,
                              void* d_out, int out_size, void* d_ws, size_t ws_size,
                              hipStream_t stream) {
    const float* x      = (const float*)d_in[0];
    const float* weight = (const float*)d_in[1];
    const float* bias   = (const float*)d_in[2];
    float* out          = (float*)d_out;

    hipLaunchKernelGGL(repack_kernel, dim3(CIN, 34), dim3(256), 0, stream, x);
    hipLaunchKernelGGL(local2d_kernel, dim3(NPOS), dim3(128), 0, stream,
                       weight, bias, out);
}

// Round 3
// 258.466 us; speedup vs baseline: 3.0853x; 1.8198x over previous
//
#include <hip/hip_runtime.h>

#define HH 32
#define WW 32
#define CIN 64
#define COUT 64
#define BATCH 32
#define KTOT 576            // CIN * 9
#define NPOS 1024
#define KC 8                // k-chunk per wave-iteration
#define KHALF 288           // K per wave (2-way K-split)
#define NCW 36              // chunks per wave = 288/8
#define WGRP 260            // 32 o-rows * 8 k + 4 floats pad (16B-aligned group stride)

// halo-padded transposed input: xT[i][34][34][b]
__device__ float g_xT[CIN * 34 * 34 * BATCH];

// Coalesced transpose repack: one block per (i, hh). Reads x rows (lanes over
// w, 128 B segments), transposes through LDS, writes g_xT rows (lanes over b,
// 128 B segments). Halo rows/cols written as zeros.
__global__ __launch_bounds__(256) void repack_kernel(const float* __restrict__ x) {
    __shared__ float tile[32 * 33];        // [b][w], pad 33 -> conflict-free
    const int i   = blockIdx.x;            // 0..63
    const int hh  = blockIdx.y;            // 0..33
    const int tid = threadIdx.x;

    float* dst = &g_xT[((i * 34 + hh) * 34) * BATCH];

    if (hh == 0 || hh == 33) {             // halo row: all zeros (34*32 floats)
        for (int idx = tid; idx < 34 * BATCH; idx += 256) dst[idx] = 0.f;
        return;
    }
    const int hs = hh - 1;
#pragma unroll
    for (int bb = 0; bb < 4; ++bb) {       // read 8 b-rows per pass
        int b = bb * 8 + (tid >> 5);
        int w = tid & 31;
        tile[b * 33 + w] = x[(b << 16) + (i << 10) + (hs << 5) + w];
    }
    __syncthreads();
#pragma unroll
    for (int q = 0; q < 5; ++q) {          // write 8 ww-rows per pass (34 total)
        int ww = q * 8 + (tid >> 5);
        if (ww < 34) {
            int b = tid & 31;
            float v = (ww == 0 || ww == 33) ? 0.f : tile[b * 33 + (ww - 1)];
            dst[ww * BATCH + b] = v;
        }
    }
}

__device__ __forceinline__ void async16(const void* src, void* dst_lds) {
    __builtin_amdgcn_global_load_lds(
        (const __attribute__((address_space(1))) void*)src,
        (__attribute__((address_space(3))) void*)dst_lds,
        16, 0, 0);
}

// 128 threads = 2 waves per block; wave w computes K in [w*288, w*288+288).
// 3-deep LDS pipeline per wave (round-0 loop shape, which compiles spill-free);
// 3 DMAs per chunk -> vmcnt(3) = chunk c landed, chunk c+1 still in flight.
// KC=8 shrinks LDS to 18.7 KB -> 8 blocks/CU -> 4 waves/SIMD (round 0: 2).
__global__ __launch_bounds__(128, 2) void local2d_kernel(
    const float* __restrict__ weight,
    const float* __restrict__ bias,
    float* __restrict__ out)
{
    // per-wave private staging: [wave][buf][...]
    __shared__ float Wl[2][3][2 * WGRP];   // 2 groups x (32 o-rows x 8 k + pad)
    __shared__ float Pl[2][3][KC * BATCH]; // 8 k x 32 b

    const int wv = threadIdx.x >> 6;       // wave id 0/1
    const int l  = threadIdx.x & 63;       // lane

    const int og = l & 7, bg = l >> 3;     // compute roles: o-group, b-group

    // row-granular XCD swizzle: each XCD owns whole output rows ->
    // 32-consecutive-p runs = full 128 B out lines from one XCD; W stream and
    // g_xT row reads contiguous per XCD.
    int bid = blockIdx.x;
    int xcd = bid & 7;
    int t   = bid >> 3;                    // 0..127
    int y   = ((t >> 5) << 3) | xcd;       // {xcd, 8+xcd, 16+xcd, 24+xcd}
    int xw  = t & 31;
    int p   = (y << 5) | xw;               // position = y*32 + x

    const int kbase = wv * KHALF;
    const float* wpos  = weight + (long)p * (COUT * KTOT);
    // W DMA lane role: row l>>1 (of 32-row group), col (l&1)*4 floats
    const float* wsrc0 = wpos + (l >> 1) * KTOT + ((l & 1) << 2) + kbase;

    float acc[8][4];
#pragma unroll
    for (int a = 0; a < 8; ++a)
#pragma unroll
        for (int c = 0; c < 4; ++c) acc[a][c] = 0.f;

    auto stage = [&](int c, int bsel) {
        const float* ws = wsrc0 + c * KC;
        // W chunk: 64 o x 8 k; DMA g covers o-rows [32g,32g+32)
#pragma unroll
        for (int g = 0; g < 2; ++g)
            async16(ws + g * (32 * KTOT), &Wl[wv][bsel][g * WGRP]);
        // P chunk: 8 k x 32 b = 1024 B contig, one DMA
        {
            int k  = kbase + c * KC + (l >> 3);
            int i  = k / 9;
            int r  = k - i * 9;
            int kh = r / 3;
            int kw = r - kh * 3;
            const float* ps =
                &g_xT[(((i * 34) + y + kh) * 34 + xw + kw) * BATCH + ((l & 7) << 2)];
            async16(ps, &Pl[wv][bsel][0]);
        }
    };

    auto compute = [&](int bsel) {
        // lane reads o = og*8+oo -> group og>>2, local row (og&3)*8+oo
        const float* Wb = &Wl[wv][bsel][(og >> 2) * WGRP + ((og & 3) << 3) * KC];
        const float* Pb = &Pl[wv][bsel][bg << 2];
#pragma unroll
        for (int kk = 0; kk < KC; kk += 4) {
            float4 pr[4];
#pragma unroll
            for (int j = 0; j < 4; ++j)
                pr[j] = *(const float4*)(Pb + (kk + j) * BATCH);
            const float* prf = (const float*)pr;
#pragma unroll
            for (int oo = 0; oo < 8; ++oo) {
                float4 wr = *(const float4*)(Wb + oo * KC + kk);
#pragma unroll
                for (int bb = 0; bb < 4; ++bb) {
                    float a = acc[oo][bb];
                    a = fmaf(wr.x, prf[0 * 4 + bb], a);
                    a = fmaf(wr.y, prf[1 * 4 + bb], a);
                    a = fmaf(wr.z, prf[2 * 4 + bb], a);
                    a = fmaf(wr.w, prf[3 * 4 + bb], a);
                    acc[oo][bb] = a;
                }
            }
        }
    };

    stage(0, 0);
    stage(1, 1);
    for (int c = 0; c < NCW - 1; ++c) {
        // chunk c's 3 DMAs are the oldest; <=3 left => chunk c landed
        asm volatile("s_waitcnt vmcnt(3)" ::: "memory");
        // WAR guard: reads of buf (c+2)%3 were issued in compute(c-1), long
        // retired -> this drain is ~free but guarantees sampling order.
        asm volatile("s_waitcnt lgkmcnt(0)" ::: "memory");
        if (c + 2 < NCW) stage(c + 2, (c + 2) % 3);
        compute(c % 3);
    }
    asm volatile("s_waitcnt vmcnt(0)" ::: "memory");
    compute((NCW - 1) % 3);

    // ---- cross-wave reduction: wave1 dumps partials, wave0 sums + stores ----
    __syncthreads();                       // both waves done with staging bufs
    float* R = &Wl[0][0][0];               // 64 o x 32 b, stride 36 (bank spread)
    if (wv == 1) {
#pragma unroll
        for (int oo = 0; oo < 8; ++oo) {
            int o = (og << 3) + oo;
            *(float4*)(&R[o * 36 + (bg << 2)]) =
                make_float4(acc[oo][0], acc[oo][1], acc[oo][2], acc[oo][3]);
        }
    }
    __syncthreads();
    if (wv == 0) {
#pragma unroll
        for (int oo = 0; oo < 8; ++oo) {
            int o = (og << 3) + oo;
            float bv = bias[(o << 10) + p];
            float4 r = *(const float4*)(&R[o * 36 + (bg << 2)]);
            const float* rf = (const float*)&r;
#pragma unroll
            for (int bb = 0; bb < 4; ++bb) {
                int b = (bg << 2) + bb;
                out[(b << 16) + (o << 10) + p] = acc[oo][bb] + rf[bb] + bv;
            }
        }
    }
}

extern "C" void kernel_launch(void* const* d_in, const int* in_sizes, int n_in,
                              void* d_out, int out_size, void* d_ws, size_t ws_size,
                              hipStream_t stream) {
    const float* x      = (const float*)d_in[0];
    const float* weight = (const float*)d_in[1];
    const float* bias   = (const float*)d_in[2];
    float* out          = (float*)d_out;

    hipLaunchKernelGGL(repack_kernel, dim3(CIN, 34), dim3(256), 0, stream, x);
    hipLaunchKernelGGL(local2d_kernel, dim3(NPOS), dim3(128), 0, stream,
                       weight, bias, out);
}

// Round 4
// 252.886 us; speedup vs baseline: 3.1534x; 1.0221x over previous
//
#include <hip/hip_runtime.h>

#define HH 32
#define WW 32
#define CIN 64
#define COUT 64
#define BATCH 32
#define KTOT 576            // CIN * 9
#define NPOS 1024
#define KC 8                // k-chunk per wave-iteration
#define KHALF 288           // K per wave (2-way K-split)
#define NCW 36              // chunks per wave = 288/8

// halo-padded transposed input: xT[i][34][34][b]
__device__ float g_xT[CIN * 34 * 34 * BATCH];

// Coalesced transpose repack: one block per (i, hh). Reads x rows (lanes over
// w, 128 B segments), transposes through LDS, writes g_xT rows (lanes over b,
// 128 B segments). Halo rows/cols written as zeros.
__global__ __launch_bounds__(256) void repack_kernel(const float* __restrict__ x) {
    __shared__ float tile[32 * 33];        // [b][w], pad 33 -> conflict-free
    const int i   = blockIdx.x;            // 0..63
    const int hh  = blockIdx.y;            // 0..33
    const int tid = threadIdx.x;

    float* dst = &g_xT[((i * 34 + hh) * 34) * BATCH];

    if (hh == 0 || hh == 33) {             // halo row: all zeros (34*32 floats)
        for (int idx = tid; idx < 34 * BATCH; idx += 256) dst[idx] = 0.f;
        return;
    }
    const int hs = hh - 1;
#pragma unroll
    for (int bb = 0; bb < 4; ++bb) {       // read 8 b-rows per pass
        int b = bb * 8 + (tid >> 5);
        int w = tid & 31;
        tile[b * 33 + w] = x[(b << 16) + (i << 10) + (hs << 5) + w];
    }
    __syncthreads();
#pragma unroll
    for (int q = 0; q < 5; ++q) {          // write 8 ww-rows per pass (34 total)
        int ww = q * 8 + (tid >> 5);
        if (ww < 34) {
            int b = tid & 31;
            float v = (ww == 0 || ww == 33) ? 0.f : tile[b * 33 + (ww - 1)];
            dst[ww * BATCH + b] = v;
        }
    }
}

__device__ __forceinline__ void async16(const void* src, void* dst_lds) {
    __builtin_amdgcn_global_load_lds(
        (const __attribute__((address_space(1))) void*)src,
        (__attribute__((address_space(3))) void*)dst_lds,
        16, 0, 0);
}

// Grid 2048 = (position p) x (cout-half oh): 8 blocks/CU -> 4 waves/SIMD
// (round 3 was grid-limited to 2 waves/SIMD). 128 threads = 2 waves; wave wv
// computes K in [wv*288, wv*288+288) for 32 couts x 32 batch.
// 3-deep pipeline, round-3 loop shape (spill-free); 2 DMAs/chunk -> vmcnt(2).
//
// W LDS layout (m173 source permutation, conflict-free reads):
//   granule idx = oo*16 + kq*8 + og  (granule = 16 B; oo=o&3.. see below)
//   DMA lane l fetches W row o=(l&7)*4+(l>>4), k-granule kq=(l>>3)&1 ->
//   read at fixed (oo,kq): 8 og-lanes stride 16 B = all 32 banks once.
__global__ __launch_bounds__(128, 2) void local2d_kernel(
    const float* __restrict__ weight,
    const float* __restrict__ bias,
    float* __restrict__ out)
{
    // per-wave private staging: [wave][buf][...]
    __shared__ float Wl[2][3][32 * KC];    // 32 o x 8 k, permuted granules
    __shared__ float Pl[2][3][KC * BATCH]; // 8 k x 32 b

    const int wv = threadIdx.x >> 6;       // wave id 0/1
    const int l  = threadIdx.x & 63;       // lane

    const int og = l & 7, bg = l >> 3;     // compute roles: o-group, b-group

    // XCD swizzle: xcd owns whole output rows; the two oh-halves of a
    // position are dispatch-adjacent on the same XCD -> g_xT L2 reuse.
    int bid = blockIdx.x;
    int xcd = bid & 7;
    int t   = bid >> 3;                    // 0..255
    int oh  = t & 1;                       // cout half
    int tt  = t >> 1;                      // 0..127
    int y   = ((tt >> 5) << 3) | xcd;      // {xcd, 8+xcd, 16+xcd, 24+xcd}
    int xw  = tt & 31;
    int p   = (y << 5) | xw;               // position = y*32 + x

    const int kbase = wv * KHALF;
    const float* wpos = weight + ((long)p * COUT + (oh << 5)) * KTOT;
    // W DMA lane role: row (l&7)*4+(l>>4), k-granule (l>>3)&1
    const float* wsrc0 =
        wpos + (((l & 7) << 2) + (l >> 4)) * KTOT + (((l >> 3) & 1) << 2) + kbase;

    float acc[4][4];
#pragma unroll
    for (int a = 0; a < 4; ++a)
#pragma unroll
        for (int c = 0; c < 4; ++c) acc[a][c] = 0.f;

    auto stage = [&](int c, int bsel) {
        // W chunk: 32 o x 8 k = 1024 B, one DMA (permuted source)
        async16(wsrc0 + c * KC, &Wl[wv][bsel][0]);
        // P chunk: 8 k x 32 b = 1024 B, one DMA
        {
            int k  = kbase + c * KC + (l >> 3);
            int i  = k / 9;
            int r  = k - i * 9;
            int kh = r / 3;
            int kw = r - kh * 3;
            const float* ps =
                &g_xT[(((i * 34) + y + kh) * 34 + xw + kw) * BATCH + ((l & 7) << 2)];
            async16(ps, &Pl[wv][bsel][0]);
        }
    };

    auto compute = [&](int bsel) {
        const float* Wb = &Wl[wv][bsel][og << 2];
        const float* Pb = &Pl[wv][bsel][bg << 2];
#pragma unroll
        for (int kk = 0; kk < KC; kk += 4) {
            float4 pr[4];
#pragma unroll
            for (int j = 0; j < 4; ++j)
                pr[j] = *(const float4*)(Pb + (kk + j) * BATCH);
            const float* prf = (const float*)pr;
#pragma unroll
            for (int oo = 0; oo < 4; ++oo) {
                // granule (oo, kq=kk>>2, og) -> float offset oo*64+kq*32+og*4
                float4 wr = *(const float4*)(Wb + (oo << 6) + (kk << 3));
#pragma unroll
                for (int bb = 0; bb < 4; ++bb) {
                    float a = acc[oo][bb];
                    a = fmaf(wr.x, prf[0 * 4 + bb], a);
                    a = fmaf(wr.y, prf[1 * 4 + bb], a);
                    a = fmaf(wr.z, prf[2 * 4 + bb], a);
                    a = fmaf(wr.w, prf[3 * 4 + bb], a);
                    acc[oo][bb] = a;
                }
            }
        }
    };

    stage(0, 0);
    stage(1, 1);
    for (int c = 0; c < NCW - 1; ++c) {
        // chunk c's 2 DMAs are the oldest; <=2 left => chunk c landed,
        // chunk c+1 still in flight across this compute phase.
        asm volatile("s_waitcnt vmcnt(2)" ::: "memory");
        // WAR guard: reads of buf (c+2)%3 were issued in compute(c-1), long
        // retired -> this drain is ~free but guarantees sampling order.
        asm volatile("s_waitcnt lgkmcnt(0)" ::: "memory");
        if (c + 2 < NCW) stage(c + 2, (c + 2) % 3);
        compute(c % 3);
    }
    asm volatile("s_waitcnt vmcnt(0)" ::: "memory");
    compute((NCW - 1) % 3);

    // ---- cross-wave reduction: wave1 dumps partials, wave0 sums + stores ----
    __syncthreads();                       // both waves done with staging bufs
    float* R = &Wl[0][0][0];               // 32 o x 32 b, stride 36 (1152 <= 1536)
    if (wv == 1) {
#pragma unroll
        for (int oo = 0; oo < 4; ++oo) {
            int o = (og << 2) + oo;
            *(float4*)(&R[o * 36 + (bg << 2)]) =
                make_float4(acc[oo][0], acc[oo][1], acc[oo][2], acc[oo][3]);
        }
    }
    __syncthreads();
    if (wv == 0) {
#pragma unroll
        for (int oo = 0; oo < 4; ++oo) {
            int o  = (og << 2) + oo;
            int of = (oh << 5) + o;        // global cout
            float bv = bias[(of << 10) + p];
            float4 r = *(const float4*)(&R[o * 36 + (bg << 2)]);
            const float* rf = (const float*)&r;
#pragma unroll
            for (int bb = 0; bb < 4; ++bb) {
                int b = (bg << 2) + bb;
                out[(b << 16) + (of << 10) + p] = acc[oo][bb] + rf[bb] + bv;
            }
        }
    }
}

extern "C" void kernel_launch(void* const* d_in, const int* in_sizes, int n_in,
                              void* d_out, int out_size, void* d_ws, size_t ws_size,
                              hipStream_t stream) {
    const float* x      = (const float*)d_in[0];
    const float* weight = (const float*)d_in[1];
    const float* bias   = (const float*)d_in[2];
    float* out          = (float*)d_out;

    hipLaunchKernelGGL(repack_kernel, dim3(CIN, 34), dim3(256), 0, stream, x);
    hipLaunchKernelGGL(local2d_kernel, dim3(2 * NPOS), dim3(128), 0, stream,
                       weight, bias, out);
}